// Round 3
// baseline (181.994 us; speedup 1.0000x reference)
//
#include <hip/hip_runtime.h>

#define NROW 8192
#define FIN  512
#define FOUT 256
#define ALPHA 0.2f

typedef float  f32x4  __attribute__((ext_vector_type(4)));
typedef int    i32x4  __attribute__((ext_vector_type(4)));
typedef __bf16 bf16x8 __attribute__((ext_vector_type(8)));
typedef __bf16 bf16x4 __attribute__((ext_vector_type(4)));

// ---------------- K1: WbT[f][k] = bf16(W[k][f]) ----------------
__global__ void k1_wt(const float* __restrict__ W, unsigned short* __restrict__ WbT_u) {
    __bf16* WbT = (__bf16*)WbT_u;
    __shared__ float tw[32][33];
    int bx = blockIdx.x & 7;    // f tile (8 x 32 = 256)
    int by = blockIdx.x >> 3;   // k tile (16 x 32 = 512)
    int f0 = bx * 32, k0 = by * 32;
    int tx = threadIdx.x & 31, ty = threadIdx.x >> 5;  // ty 0..7
#pragma unroll
    for (int r = 0; r < 4; ++r)
        tw[ty + 8*r][tx] = W[(k0 + ty + 8*r) * FOUT + f0 + tx];
    __syncthreads();
#pragma unroll
    for (int r = 0; r < 4; ++r)
        WbT[(f0 + ty + 8*r) * FIN + k0 + tx] = (__bf16)tw[tx][ty + 8*r];
}

// ---------------- K2: hT[f][i] = sum_k WT[f][k] * x[i][k]  (bf16 MFMA) ----------------
__global__ __launch_bounds__(256, 2) void k2_gemm1(const float* __restrict__ x,
                                                   const unsigned short* __restrict__ WbT_u,
                                                   unsigned short* __restrict__ hTb_u) {
    const __bf16* WbT = (const __bf16*)WbT_u;
    __bf16* hTb = (__bf16*)hTb_u;
    int i0 = blockIdx.x * 32;
    int t = threadIdx.x;
    int lane = t & 63, wv = t >> 6;
    int lm = lane & 15, lg = lane >> 4;
    int wf0 = wv * 64;  // wave's 64-f slice

    f32x4 acc[4][2];
#pragma unroll
    for (int a = 0; a < 4; ++a)
#pragma unroll
        for (int b = 0; b < 2; ++b) acc[a][b] = (f32x4){0.f, 0.f, 0.f, 0.f};

    for (int kt = 0; kt < FIN; kt += 32) {
        bf16x8 af[4];
#pragma unroll
        for (int fi = 0; fi < 4; ++fi)
            af[fi] = *(const bf16x8*)(WbT + (wf0 + fi*16 + lm) * FIN + kt + lg*8);
        bf16x8 bfr[2];
#pragma unroll
        for (int ii = 0; ii < 2; ++ii) {
            const float* xp = x + (i0 + ii*16 + lm) * FIN + kt + lg*8;
            f32x4 v0 = *(const f32x4*)(xp);
            f32x4 v1 = *(const f32x4*)(xp + 4);
            bf16x8 b;
#pragma unroll
            for (int e = 0; e < 4; ++e) { b[e] = (__bf16)v0[e]; b[4+e] = (__bf16)v1[e]; }
            bfr[ii] = b;
        }
#pragma unroll
        for (int fi = 0; fi < 4; ++fi)
#pragma unroll
            for (int ii = 0; ii < 2; ++ii)
                acc[fi][ii] = __builtin_amdgcn_mfma_f32_16x16x32_bf16(af[fi], bfr[ii], acc[fi][ii], 0, 0, 0);
    }
    // D: row(f) = lg*4+q, col(i) = lm   [verified m89 layout]
#pragma unroll
    for (int fi = 0; fi < 4; ++fi)
#pragma unroll
        for (int ii = 0; ii < 2; ++ii)
#pragma unroll
            for (int q = 0; q < 4; ++q)
                hTb[(wf0 + fi*16 + lg*4 + q) * NROW + i0 + ii*16 + lm] = (__bf16)acc[fi][ii][q];
}

// ---------------- K3a: l1,l2 ----------------
__global__ void k3_logits(const unsigned short* __restrict__ hTb_u,
                          const float* __restrict__ a1, const float* __restrict__ a2,
                          float* __restrict__ l1, float* __restrict__ l2) {
    const __bf16* hTb = (const __bf16*)hTb_u;
    int i = blockIdx.x * 256 + threadIdx.x;
    float s1 = 0.f, s2 = 0.f;
    for (int f = 0; f < FOUT; ++f) {
        float h = (float)hTb[f * NROW + i];
        s1 += h * a1[f];
        s2 += h * a2[f];
    }
    l1[i] = s1; l2[i] = s2;
}

// ---------------- K3b: mean_h ----------------
__global__ void k3_mean(const unsigned short* __restrict__ hTb_u, float* __restrict__ mean_h) {
    const __bf16* hTb = (const __bf16*)hTb_u;
    int f = blockIdx.x;
    int t = threadIdx.x;
    float s = 0.f;
    for (int i = t; i < NROW; i += 256) s += (float)hTb[f * NROW + i];
#pragma unroll
    for (int m = 1; m < 64; m <<= 1) s += __shfl_xor(s, m);
    __shared__ float red[4];
    if ((t & 63) == 0) red[t >> 6] = s;
    __syncthreads();
    if (t == 0) mean_h[f] = (red[0] + red[1] + red[2] + red[3]) * (1.0f / NROW);
}

// ---------------- K3c: eg = exp(lrelu(l1 + mean_h . a2)) ----------------
__global__ void k3_eg(const float* __restrict__ l1, const float* __restrict__ mean_h,
                      const float* __restrict__ a2, float* __restrict__ eg) {
    __shared__ float red[5];
    int t = threadIdx.x;
    float v = mean_h[t] * a2[t];
#pragma unroll
    for (int m = 1; m < 64; m <<= 1) v += __shfl_xor(v, m);
    if ((t & 63) == 0) red[t >> 6] = v;
    __syncthreads();
    if (t == 0) red[4] = red[0] + red[1] + red[2] + red[3];
    __syncthreads();
    float mda2 = red[4];
    int i = blockIdx.x * 256 + t;
    float g = l1[i] + mda2;
    eg[i] = __expf(fmaxf(g, ALPHA * g));
}

// ---------------- K4: fused masked-softmax-weighted GEMM (partials over j-splits) ----------------
__global__ __launch_bounds__(256, 2) void k4_attn(const int* __restrict__ adj,
                                                  const unsigned short* __restrict__ hTb_u,
                                                  const float* __restrict__ l1,
                                                  const float* __restrict__ l2,
                                                  float* __restrict__ outpT,
                                                  float* __restrict__ Zp,
                                                  int js, int jwidth, int ntiles) {
    const __bf16* hTb = (const __bf16*)hTb_u;
    __shared__ __align__(16) __bf16 wlds[64 * 64];

    int b = blockIdx.x;
    int js_idx = b % js;
    int it = b / js;
    int i0 = it * 64;
    int jstart = js_idx * jwidth;

    int t = threadIdx.x;
    int lane = t & 63, wv = t >> 6;
    int lm = lane & 15, lg = lane >> 4;
    int wf0 = wv * 64;
    int r = t >> 2, cc = t & 3;     // staging: row r (0..63), chunk cc
    int i_glob = i0 + r;
    float l1v = l1[i_glob];

    const i32x4* adj4 = (const i32x4*)adj;
    const f32x4* l24  = (const f32x4*)l2;
    long arow = (long)i_glob * (NROW / 4);

    f32x4 acc[4][4];
#pragma unroll
    for (int a = 0; a < 4; ++a)
#pragma unroll
        for (int c = 0; c < 4; ++c) acc[a][c] = (f32x4){0.f, 0.f, 0.f, 0.f};
    float zpart = 0.f;

    i32x4 adjA[4], adjB[4];
    f32x4 l2A[4], l2B[4];

    auto loadT = [&](i32x4 (&adjR)[4], f32x4 (&l2R)[4], int jb) {
        int c4 = jb >> 2;
#pragma unroll
        for (int k = 0; k < 4; ++k) {
            adjR[k] = adj4[arow + c4 + cc + 4*k];
            l2R[k]  = l24[c4 + cc + 4*k];
        }
    };

    auto procT = [&](i32x4 (&adjR)[4], f32x4 (&l2R)[4], int jb) {
        bf16x4 pk[4];
        float zadd = 0.f;
#pragma unroll
        for (int k = 0; k < 4; ++k) {
            bf16x4 p;
#pragma unroll
            for (int e = 0; e < 4; ++e) {
                float s = l1v + l2R[k][e];
                float w = (adjR[k][e] > 0) ? __expf(fmaxf(s, ALPHA * s)) : 0.0f;
                __bf16 wb = (__bf16)w;
                p[e] = wb;
                zadd += (float)wb;   // Z consistent with bf16-rounded numerator
            }
            pk[k] = p;
        }
        zpart += zadd;
        __syncthreads();   // previous MFMA done reading wlds
#pragma unroll
        for (int k = 0; k < 4; ++k) {
            int jl = cc * 4 + 16 * k;
            int blk = jl >> 3;
            int eo = r * 64 + ((blk ^ (r & 7)) << 3) + (jl & 7);   // XOR swizzle (G4)
            *(bf16x4*)(wlds + eo) = pk[k];
        }
        __syncthreads();   // wlds ready
#pragma unroll
        for (int ks = 0; ks < 2; ++ks) {
            bf16x8 af[4];
#pragma unroll
            for (int fi = 0; fi < 4; ++fi)
                af[fi] = *(const bf16x8*)(hTb + (wf0 + fi*16 + lm) * NROW + jb + ks*32 + lg*8);
            bf16x8 bw[4];
#pragma unroll
            for (int ii = 0; ii < 4; ++ii) {
                int row = ii * 16 + lm;
                int blk = ks * 4 + lg;
                bw[ii] = *(const bf16x8*)(wlds + row * 64 + ((blk ^ (row & 7)) << 3));
            }
#pragma unroll
            for (int fi = 0; fi < 4; ++fi)
#pragma unroll
                for (int ii = 0; ii < 4; ++ii)
                    acc[fi][ii] = __builtin_amdgcn_mfma_f32_16x16x32_bf16(af[fi], bw[ii], acc[fi][ii], 0, 0, 0);
        }
    };

    loadT(adjA, l2A, jstart);
    for (int tt = 0; tt < ntiles; tt += 2) {
        loadT(adjB, l2B, jstart + (tt + 1) * 64);
        procT(adjA, l2A, jstart + tt * 64);
        if (tt + 2 < ntiles) loadT(adjA, l2A, jstart + (tt + 2) * 64);
        procT(adjB, l2B, jstart + (tt + 1) * 64);
    }

    // Z row-reduce over the 4 staging threads per row
    float zs = zpart + __shfl_xor(zpart, 1);
    zs += __shfl_xor(zs, 2);
    if (cc == 0) Zp[js_idx * NROW + i_glob] = zs;

    // store transposed partials: outpT[js][f][i]
#pragma unroll
    for (int fi = 0; fi < 4; ++fi)
#pragma unroll
        for (int ii = 0; ii < 4; ++ii)
#pragma unroll
            for (int q = 0; q < 4; ++q)
                outpT[js_idx * (NROW * FOUT) + (wf0 + fi*16 + lg*4 + q) * NROW + i0 + ii*16 + lm] = acc[fi][ii][q];
}

// ---------------- K5: combine partials + global term + softmax div + elu + transpose ----------------
__global__ void k5_final(const float* __restrict__ outpT, const float* __restrict__ Zp,
                         const float* __restrict__ eg, const float* __restrict__ mean_h,
                         float* __restrict__ out, int js) {
    __shared__ float tile[64][65];
    int b = blockIdx.x;
    int it = b >> 2, ft = b & 3;
    int i0 = it * 64, f0 = ft * 64;
    int t = threadIdx.x;
    {
        int fl = t >> 2, icb = (t & 3) * 16;
#pragma unroll
        for (int c = 0; c < 4; ++c) {
            f32x4 v = (f32x4){0.f, 0.f, 0.f, 0.f};
            for (int s = 0; s < js; ++s) {
                f32x4 u = *(const f32x4*)(outpT + s * (NROW * FOUT) + (f0 + fl) * NROW + i0 + icb + 4*c);
                v += u;
            }
#pragma unroll
            for (int e = 0; e < 4; ++e) tile[fl][icb + 4*c + e] = v[e];
        }
    }
    __syncthreads();
    int il = t >> 2, fcb = (t & 3) * 16;
    int i = i0 + il;
    float egi = eg[i];
    float z = egi;
    for (int s = 0; s < js; ++s) z += Zp[s * NROW + i];
#pragma unroll
    for (int c = 0; c < 4; ++c) {
        f32x4 o;
#pragma unroll
        for (int e = 0; e < 4; ++e) {
            int fl = fcb + 4*c + e;
            float num = tile[fl][il] + egi * mean_h[f0 + fl];
            float val = num / z;
            o[e] = val > 0.f ? val : (__expf(val) - 1.0f);
        }
        *(f32x4*)(out + (long)i * FOUT + f0 + fcb + 4*c) = o;
    }
}

// ---------------- host ----------------
extern "C" void kernel_launch(void* const* d_in, const int* in_sizes, int n_in,
                              void* d_out, int out_size, void* d_ws, size_t ws_size,
                              hipStream_t stream) {
    const float* x   = (const float*)d_in[0];
    const int*   adj = (const int*)d_in[1];
    const float* W   = (const float*)d_in[2];
    const float* a1  = (const float*)d_in[3];
    const float* a2  = (const float*)d_in[4];
    float* out = (float*)d_out;
    char* ws = (char*)d_ws;

    unsigned short* hTb = (unsigned short*)(ws);                 // 4 MB
    unsigned short* WbT = (unsigned short*)(ws + 4194304);       // 256 KB
    float* l1     = (float*)(ws + 4456448);                      // 32 KB
    float* l2     = (float*)(ws + 4489216);                      // 32 KB
    float* eg     = (float*)(ws + 4521984);                      // 32 KB
    float* mean_h = (float*)(ws + 4554752);                      // 1 KB
    float* Zp     = (float*)(ws + 4555776);                      // up to 128 KB
    float* outpT  = (float*)(ws + 4687872);                      // js * 8 MB

    size_t base = 4687872;
    size_t part = (size_t)NROW * FOUT * 4;
    int js = 1;
    if (ws_size >= base + 4 * part) js = 4;
    else if (ws_size >= base + 2 * part) js = 2;
    int jwidth = NROW / js;
    int ntiles = jwidth / 64;

    hipLaunchKernelGGL(k1_wt,     dim3(128),      dim3(256), 0, stream, W, WbT);
    hipLaunchKernelGGL(k2_gemm1,  dim3(256),      dim3(256), 0, stream, x, WbT, hTb);
    hipLaunchKernelGGL(k3_logits, dim3(32),       dim3(256), 0, stream, hTb, a1, a2, l1, l2);
    hipLaunchKernelGGL(k3_mean,   dim3(256),      dim3(256), 0, stream, hTb, mean_h);
    hipLaunchKernelGGL(k3_eg,     dim3(32),       dim3(256), 0, stream, l1, mean_h, a2, eg);
    hipLaunchKernelGGL(k4_attn,   dim3(128 * js), dim3(256), 0, stream, adj, hTb, l1, l2, outpT, Zp, js, jwidth, ntiles);
    hipLaunchKernelGGL(k5_final,  dim3(512),      dim3(256), 0, stream, outpT, Zp, eg, mean_h, out, js);
}